// Round 5
// baseline (240.883 us; speedup 1.0000x reference)
//
#include <hip/hip_runtime.h>

// Leaky LIF SNN forward, x/spk: [T=128, B*N=262144] fp32.
//   reset_t = H(mem_{t-1} - 1); mem_t = 0.5*mem_{t-1} + x_t - reset_t; spk_t = H(mem_t - 1)
//
// R8 = R7b resubmit (R8's bench was an infra failure: "container failed
// twice", no kernel signal).
//
// R7b (R7 retry; compile fix only): __builtin_nontemporal_store requires a
// native clang vector type, not HIP_vector_type<float,2> -> use
// ext_vector_type(2) float alias (bit-identical, emits one 8B nt store).
//
// Theory (R7): R1 counters showed FETCH=65.6MB (half of x already
// L3-served) and WRITE=131MB -> HBM traffic ~201MB at ~79us = ~2.5-3.4
// TB/s vs 6.7 TB/s memset on the same chip. Diagnosis: the
// write-allocated out stream (134MB) + x (134MB) = 268MB > 256MB LLC, so
// out thrashes half of x out of L3, and the write stream's allocations
// pollute the channels. Fix 1: non-temporal stores for out (written once,
// never re-read here) -> x stays L3-resident across the bench's repeated
// dispatches, HBM fetch collapses, writes stream memset-style.
// Fix 2 (geometry): 256 blocks x 512 threads, float2/thread = single
// phase, one read + one write per element; the whole 4KB/CU row visit
// (1MB row / 256 CUs) is issued by ONE CU's co-scheduled 8 waves instead
// of two independently-drifting blocks on different XCDs (R6).
// No pacing barriers (R5: -32%). D=16 rolling prefetch: 128B/thread in
// flight, ~16MB device-wide (Little's law needs ~2.5MB at 6 TB/s).

#define T_STEPS 128
#define D 16   // rolling ring depth (float2 rows in flight per thread)
#define BLKT 512

typedef __attribute__((ext_vector_type(2))) float f32x2;   // native vector for nt-store

__device__ __forceinline__ float2 lif_step(float2& mem, const float2 v) {
    // RHS uses OLD mem (reset term is H(mem_{t-1} - 1))
    mem.x = 0.5f * mem.x + v.x - (mem.x > 1.0f ? 1.0f : 0.0f);
    mem.y = 0.5f * mem.y + v.y - (mem.y > 1.0f ? 1.0f : 0.0f);
    float2 s;
    s.x = mem.x > 1.0f ? 1.0f : 0.0f;
    s.y = mem.y > 1.0f ? 1.0f : 0.0f;
    return s;
}

__global__ __launch_bounds__(BLKT) void snn_leaky_fwd(const float2* __restrict__ x,
                                                      float2* __restrict__ out,
                                                      int n2) {
    const int col = blockIdx.x * BLKT + threadIdx.x;   // one float2 column/thread
    const float2* xp = x + col;
    f32x2* op = reinterpret_cast<f32x2*>(out + col);

    float2 buf[D];
    float2 mem = make_float2(0.f, 0.f);

#pragma unroll
    for (int u = 0; u < D; ++u) buf[u] = xp[(size_t)u * n2];

#pragma unroll
    for (int t = 0; t < T_STEPS; ++t) {
        const float2 v = buf[t & (D - 1)];
        if (t + D < T_STEPS) buf[t & (D - 1)] = xp[(size_t)(t + D) * n2];
        const float2 s = lif_step(mem, v);
        // Non-temporal: out is written once and never re-read by this
        // kernel; keep it OUT of L2/L3 so x stays cache-resident.
        f32x2 sv;
        sv.x = s.x;
        sv.y = s.y;
        __builtin_nontemporal_store(sv, &op[(size_t)t * n2]);
    }
}

extern "C" void kernel_launch(void* const* d_in, const int* in_sizes, int n_in,
                              void* d_out, int out_size, void* d_ws, size_t ws_size,
                              hipStream_t stream) {
    const float2* x = (const float2*)d_in[0];
    float2* out = (float2*)d_out;

    const int total = in_sizes[0];            // T*B*N = 128*64*4096
    const int n2 = total / T_STEPS / 2;       // 131072 float2 columns

    // 256 blocks x 512 threads = 131072 threads = n2: every float2 column
    // owned by exactly one thread; 1 block/CU, 8 waves/CU, single phase,
    // 4KB contiguous visit per CU per row.
    snn_leaky_fwd<<<n2 / BLKT, BLKT, 0, stream>>>(x, out, n2);
}